// Round 4
// baseline (138.323 us; speedup 1.0000x reference)
//
#include <hip/hip_runtime.h>
#include <hip/hip_bf16.h>
#include <math.h>

#define HW 4096
#define LN_EPS 1e-5f

typedef _Float16 half4v __attribute__((ext_vector_type(4)));
typedef _Float16 half8v __attribute__((ext_vector_type(8)));
typedef float float4v __attribute__((ext_vector_type(4)));
typedef __fp16 fp16v2 __attribute__((ext_vector_type(2)));

#if __has_builtin(__builtin_amdgcn_exp2f)
#define EXP2F(x) __builtin_amdgcn_exp2f(x)
#else
#define EXP2F(x) exp2f(x)
#endif

// async global->LDS: each lane deposits 16B at ldsbase + lane*16
__device__ __forceinline__ void gload_lds16(const _Float16* g, _Float16* l) {
#if __has_builtin(__builtin_amdgcn_global_load_lds)
    __builtin_amdgcn_global_load_lds(
        (const __attribute__((address_space(1))) void*)(const void*)g,
        (__attribute__((address_space(3))) void*)(void*)l, 16, 0, 0);
#else
    int lane = threadIdx.x & 63;
    *(half8v*)(l + lane * 8) = *(const half8v*)g;
#endif
}

// ---------------- kernel 1: prep (weights f16 + pos bilinear) AND x transpose ----------
__global__ __launch_bounds__(256) void k_pre(const float* __restrict__ x,
                                             const float* __restrict__ wq,
                                             const float* __restrict__ wp,
                                             const float* __restrict__ pb,
                                             _Float16* __restrict__ xt,
                                             _Float16* __restrict__ wqh,
                                             _Float16* __restrict__ wph,
                                             float* __restrict__ pos) {
    int bx = blockIdx.x, t = threadIdx.x;
    if (bx < 512) { // transpose x [512][4096] f32 -> xt [4096][512] f16
        __shared__ _Float16 tile[64][65];
        int c0 = (bx >> 6) * 64, p0 = (bx & 63) * 64;
        int w = t >> 6, lane = t & 63;
        #pragma unroll
        for (int r = 0; r < 16; r++)
            tile[w * 16 + r][lane] = (_Float16)x[(c0 + w * 16 + r) * HW + p0 + lane];
        __syncthreads();
        int cg = (t & 15) * 4, pr = t >> 4;
        #pragma unroll
        for (int r = 0; r < 4; r++) {
            int p = pr + r * 16;
            half4v v;
            #pragma unroll
            for (int k = 0; k < 4; k++) v[k] = tile[cg + k][p];
            *(half4v*)&xt[(p0 + p) * 512 + c0 + cg] = v;
        }
        return;
    }
    int i = (bx - 512) * 256 + t;
    const float qs = 0.17677669529663687f * 1.4426950408889634f; // scale * log2(e)
    if (i < 49152) { // wq: 768*512/8 chunks; Q rows pre-scaled
        float s = (i < 16384) ? qs : 1.0f;
        float4v a = *(const float4v*)(wq + i * 8);
        float4v b = *(const float4v*)(wq + i * 8 + 4);
        half8v h;
        #pragma unroll
        for (int k = 0; k < 4; k++) { h[k] = (_Float16)(a[k] * s); h[4 + k] = (_Float16)(b[k] * s); }
        *(half8v*)(wqh + i * 8) = h;
    } else if (i < 65536) { // wp
        int j = i - 49152;
        float4v a = *(const float4v*)(wp + j * 8);
        float4v b = *(const float4v*)(wp + j * 8 + 4);
        half8v h;
        #pragma unroll
        for (int k = 0; k < 4; k++) { h[k] = (_Float16)a[k]; h[4 + k] = (_Float16)b[k]; }
        *(half8v*)(wph + j * 8) = h;
    } else { // pos bilinear 16->64, times log2(e)
        int j = i - 65536;
        int h = j >> 12, p = j & 4095, y = p >> 6, xx = p & 63;
        float sy = y * 0.25f - 0.375f, sx = xx * 0.25f - 0.375f;
        float fy = floorf(sy), fx = floorf(sx);
        float wy = sy - fy, wx = sx - fx;
        int y0 = (int)fy, x0 = (int)fx;
        int y1 = y0 + 1 < 15 ? y0 + 1 : 15;
        int x1 = x0 + 1 < 15 ? x0 + 1 : 15;
        y0 = y0 > 0 ? y0 : 0;
        x0 = x0 > 0 ? x0 : 0;
        const float* src = pb + h * 256;
        float v = (1.f - wy) * ((1.f - wx) * src[y0 * 16 + x0] + wx * src[y0 * 16 + x1]) +
                  wy * ((1.f - wx) * src[y1 * 16 + x0] + wx * src[y1 * 16 + x1]);
        pos[j] = v * 1.4426950408889634f;
    }
}

// ---------------- kernel 2: QKV GEMM, LDS-free, 64n x 64p tiles (grid 768, 3 blk/CU) --
// Outputs: qa [h][q][d] row-major; ka/va as raw MFMA fragment streams per 32-j pair:
//   ka: pair record = 2 windows x 512 halfs. Window w (0/1) holds j's with ((j&7)>>2)==w,
//       MFMA-local row = (j5>>3)*4 + (j5&3); lane=(d>>3)*16+row, idx=d&7  (K=32 A-frag)
//   va: pair record = 1024 halfs: [d-half (d>>4)][lane=(j5>>3)*16+(d&15)][idx=j5&7]
//       -> per-lane contiguous 16B, K=32 B-frag (k = (lane>>4)*8 + idx = j5)
__global__ __launch_bounds__(256) void k_qkv(const _Float16* __restrict__ wqh,
                                             const _Float16* __restrict__ xt,
                                             _Float16* __restrict__ qa,
                                             _Float16* __restrict__ ka,
                                             _Float16* __restrict__ va) {
    int n0 = (blockIdx.x >> 6) * 64;
    int p0 = (blockIdx.x & 63) * 64;
    int t = threadIdx.x, w = t >> 6, lane = t & 63, quad = lane >> 4, l16 = lane & 15;

    const _Float16* aptr = xt + (p0 + w * 16 + l16) * 512 + quad * 8;
    const _Float16* bptr = wqh + (n0 + l16) * 512 + quad * 8;

    float4v acc[4] = {};
    #pragma unroll 4
    for (int kc = 0; kc < 16; kc++) {
        half8v a0 = *(const half8v*)(aptr + kc * 32);
        #pragma unroll
        for (int nt = 0; nt < 4; nt++) {
            half8v b = *(const half8v*)(bptr + nt * 16 * 512 + kc * 32);
            acc[nt] = __builtin_amdgcn_mfma_f32_16x16x32_f16(a0, b, acc[nt], 0, 0, 0);
        }
    }
    #pragma unroll
    for (int nt = 0; nt < 4; nt++) {
        int o = n0 + nt * 16 + l16;
        #pragma unroll
        for (int r = 0; r < 4; r++) {
            int p = p0 + w * 16 + quad * 4 + r;
            _Float16 v = (_Float16)acc[nt][r];
            if (o < 256) {
                qa[(o >> 5) * 131072 + p * 32 + (o & 31)] = v;
            } else if (o < 512) {
                int oc = o - 256, hh = oc >> 5, d = oc & 31;
                int p5 = p & 31, pair = p >> 5;
                int window = (p5 >> 2) & 1;
                int localrow = (p5 >> 3) * 4 + (p5 & 3);
                ka[hh * 131072 + (pair * 2 + window) * 512 +
                   ((d >> 3) * 16 + localrow) * 8 + (d & 7)] = v;
            } else {
                int oc = o - 512, hh = oc >> 5, d = oc & 31;
                int p5 = p & 31, pair = p >> 5;
                va[hh * 131072 + pair * 1024 + (d >> 4) * 512 +
                   ((p5 >> 3) * 16 + (d & 15)) * 8 + (p5 & 7)] = v;
            }
        }
    }
}

// ---------------- kernel 3: flash attention, async-LDS double buffer, j-split x2 -------
// grid 512 = 8 heads x 2 j-halves x 32 q-blocks; block = 128 q (4 waves x 32 q).
// 16 tiles of 128 j, paired-window K=32 PV MFMAs, f16 partial outputs.
// lsum computed via MFMA with all-ones B fragment (no fdot2 chain, no shfl reduce).
__global__ __launch_bounds__(256, 4) void k_attn(const _Float16* __restrict__ qa,
                                                 const _Float16* __restrict__ ka,
                                                 const _Float16* __restrict__ va,
                                                 const float* __restrict__ pos,
                                                 _Float16* __restrict__ op,
                                                 float* __restrict__ lp) {
    __shared__ __attribute__((aligned(16))) _Float16 kbuf[2][4096];
    __shared__ __attribute__((aligned(16))) _Float16 vbuf[2][4096];
    __shared__ __attribute__((aligned(16))) float posl[2048];
    int h = blockIdx.x & 7;
    int jq = (blockIdx.x >> 3) & 1;
    int qb = blockIdx.x >> 4;
    int t = threadIdx.x, w = t >> 6, lane = t & 63, quad = lane >> 4, l16 = lane & 15;
    int q0 = qb * 128 + w * 32;

    _Float16* opp = op + jq * 1048576;
    float* lpp = lp + jq * 32768;

    // stage pos half (2048 floats)
    *(float4v*)(posl + t * 8) = *(const float4v*)(pos + h * HW + jq * 2048 + t * 8);
    *(float4v*)(posl + t * 8 + 4) = *(const float4v*)(pos + h * HW + jq * 2048 + t * 8 + 4);

    half8v qf0 = *(const half8v*)(qa + h * 131072 + (q0 + l16) * 32 + quad * 8);
    half8v qf1 = *(const half8v*)(qa + h * 131072 + (q0 + 16 + l16) * 32 + quad * 8);

    const _Float16* kg = ka + h * 131072 + jq * 65536;
    const _Float16* vg = va + h * 131072 + jq * 65536;

    // issue tile 0 loads (async into LDS): 8 KB each of K and V
    gload_lds16(kg + (w * 64 + lane) * 8, &kbuf[0][w * 512]);
    gload_lds16(kg + 2048 + (w * 64 + lane) * 8, &kbuf[0][2048 + w * 512]);
    gload_lds16(vg + (w * 64 + lane) * 8, &vbuf[0][w * 512]);
    gload_lds16(vg + 2048 + (w * 64 + lane) * 8, &vbuf[0][2048 + w * 512]);

    float4v o00 = {}, o01 = {}, o10 = {}, o11 = {};
    float4v lacc0 = {}, lacc1 = {};
    const half8v ones8 = {(_Float16)1.f, (_Float16)1.f, (_Float16)1.f, (_Float16)1.f,
                          (_Float16)1.f, (_Float16)1.f, (_Float16)1.f, (_Float16)1.f};

    for (int tile = 0; tile < 16; tile++) {
        int buf = tile & 1;
        __syncthreads(); // drains this tile's async loads (vmcnt) + prior LDS reads
        if (tile + 1 < 16) {
            const _Float16* kn = kg + (tile + 1) * 4096;
            const _Float16* vn = vg + (tile + 1) * 4096;
            gload_lds16(kn + (w * 64 + lane) * 8, &kbuf[buf ^ 1][w * 512]);
            gload_lds16(kn + 2048 + (w * 64 + lane) * 8, &kbuf[buf ^ 1][2048 + w * 512]);
            gload_lds16(vn + (w * 64 + lane) * 8, &vbuf[buf ^ 1][w * 512]);
            gload_lds16(vn + 2048 + (w * 64 + lane) * 8, &vbuf[buf ^ 1][2048 + w * 512]);
        }
        #pragma unroll
        for (int pp = 0; pp < 4; pp++) {
            const _Float16* kb = &kbuf[buf][pp * 1024];
            const _Float16* vb = &vbuf[buf][pp * 1024];
            half8v kf0 = *(const half8v*)(kb + lane * 8);        // window 0: j5 = 8*quad + r
            half8v kf1 = *(const half8v*)(kb + 512 + lane * 8);  // window 1: j5 = 8*quad + 4 + r
            half8v vlo = *(const half8v*)(vb + lane * 8);        // V B-frag, d 0..15
            half8v vhi = *(const half8v*)(vb + 512 + lane * 8);  // V B-frag, d 16..31
            float4v pb0 = *(const float4v*)(posl + tile * 128 + pp * 32 + quad * 8);
            float4v pb1 = *(const float4v*)(posl + tile * 128 + pp * 32 + quad * 8 + 4);

            // S^T (rows j, cols q); pos[j] pre-added via C operand
            __builtin_amdgcn_s_setprio(1);
            float4v s00 = __builtin_amdgcn_mfma_f32_16x16x32_f16(kf0, qf0, pb0, 0, 0, 0);
            float4v s01 = __builtin_amdgcn_mfma_f32_16x16x32_f16(kf0, qf1, pb0, 0, 0, 0);
            float4v s10 = __builtin_amdgcn_mfma_f32_16x16x32_f16(kf1, qf0, pb1, 0, 0, 0);
            float4v s11 = __builtin_amdgcn_mfma_f32_16x16x32_f16(kf1, qf1, pb1, 0, 0, 0);
            __builtin_amdgcn_s_setprio(0);

            float e0 = EXP2F(s00[0]), e1 = EXP2F(s00[1]), e2 = EXP2F(s00[2]), e3 = EXP2F(s00[3]);
            float e4 = EXP2F(s10[0]), e5 = EXP2F(s10[1]), e6 = EXP2F(s10[2]), e7 = EXP2F(s10[3]);
            float f0 = EXP2F(s01[0]), f1 = EXP2F(s01[1]), f2 = EXP2F(s01[2]), f3 = EXP2F(s01[3]);
            float f4 = EXP2F(s11[0]), f5 = EXP2F(s11[1]), f6 = EXP2F(s11[2]), f7 = EXP2F(s11[3]);

            fp16v2 a01 = __builtin_amdgcn_cvt_pkrtz(e0, e1);
            fp16v2 a23 = __builtin_amdgcn_cvt_pkrtz(e2, e3);
            fp16v2 a45 = __builtin_amdgcn_cvt_pkrtz(e4, e5);
            fp16v2 a67 = __builtin_amdgcn_cvt_pkrtz(e6, e7);
            fp16v2 b01 = __builtin_amdgcn_cvt_pkrtz(f0, f1);
            fp16v2 b23 = __builtin_amdgcn_cvt_pkrtz(f2, f3);
            fp16v2 b45 = __builtin_amdgcn_cvt_pkrtz(f4, f5);
            fp16v2 b67 = __builtin_amdgcn_cvt_pkrtz(f6, f7);

            // K=32 A-fragment: k = quad*8 + i; i 0..3 <- window0 (j5=8q+i), i 4..7 <- window1
            half4v pA0 = __builtin_bit_cast(half4v, __builtin_shufflevector(a01, a23, 0, 1, 2, 3));
            half4v pA1 = __builtin_bit_cast(half4v, __builtin_shufflevector(a45, a67, 0, 1, 2, 3));
            half8v pa0 = __builtin_shufflevector(pA0, pA1, 0, 1, 2, 3, 4, 5, 6, 7);
            half4v pB0 = __builtin_bit_cast(half4v, __builtin_shufflevector(b01, b23, 0, 1, 2, 3));
            half4v pB1 = __builtin_bit_cast(half4v, __builtin_shufflevector(b45, b67, 0, 1, 2, 3));
            half8v pa1 = __builtin_shufflevector(pB0, pB1, 0, 1, 2, 3, 4, 5, 6, 7);

            __builtin_amdgcn_s_setprio(1);
            o00 = __builtin_amdgcn_mfma_f32_16x16x32_f16(pa0, vlo, o00, 0, 0, 0);
            o01 = __builtin_amdgcn_mfma_f32_16x16x32_f16(pa0, vhi, o01, 0, 0, 0);
            o10 = __builtin_amdgcn_mfma_f32_16x16x32_f16(pa1, vlo, o10, 0, 0, 0);
            o11 = __builtin_amdgcn_mfma_f32_16x16x32_f16(pa1, vhi, o11, 0, 0, 0);
            // row-sums: D[q][n] = sum_k P[q][k] * 1  (all n cols identical)
            lacc0 = __builtin_amdgcn_mfma_f32_16x16x32_f16(pa0, ones8, lacc0, 0, 0, 0);
            lacc1 = __builtin_amdgcn_mfma_f32_16x16x32_f16(pa1, ones8, lacc1, 0, 0, 0);
            __builtin_amdgcn_s_setprio(0);
        }
    }
    #pragma unroll
    for (int r = 0; r < 4; r++) {
        int qr = quad * 4 + r;
        int qi0 = q0 + qr, qi1 = q0 + 16 + qr;
        opp[qi0 * 256 + h * 32 + l16] = (_Float16)o00[r];
        opp[qi0 * 256 + h * 32 + 16 + l16] = (_Float16)o01[r];
        opp[qi1 * 256 + h * 32 + l16] = (_Float16)o10[r];
        opp[qi1 * 256 + h * 32 + 16 + l16] = (_Float16)o11[r];
    }
    if (l16 == 0) {
        #pragma unroll
        for (int r = 0; r < 4; r++) {
            lpp[(q0 + quad * 4 + r) * 8 + h] = lacc0[r];
            lpp[(q0 + 16 + quad * 4 + r) * 8 + h] = lacc1[r];
        }
    }
}

// ---------------- kernel 4: combine 2 partials + proj GEMM + residual + LayerNorm ------
__global__ __launch_bounds__(1024) void k_proj_ln(const _Float16* __restrict__ wph,
                                                  const _Float16* __restrict__ op,
                                                  const float* __restrict__ lp,
                                                  const float* __restrict__ x,
                                                  const float* __restrict__ b_proj,
                                                  const float* __restrict__ gamma,
                                                  const float* __restrict__ beta,
                                                  float* __restrict__ out) {
    __shared__ __attribute__((aligned(16))) _Float16 ys[16 * 264];
    __shared__ float red[2][16][17];
    int p0 = blockIdx.x * 16;
    int t = threadIdx.x, w = t >> 6, lane = t & 63, quad = lane >> 4, l16 = lane & 15;
    {
        int p = t >> 6, cg = (t & 63) * 4;
        int pi = p0 + p;
        half4v a0 = *(const half4v*)(op + pi * 256 + cg);
        half4v a1 = *(const half4v*)(op + 1048576 + pi * 256 + cg);
        int hh = cg >> 5;
        float l = lp[pi * 8 + hh] + lp[32768 + pi * 8 + hh];
        float inv = 1.f / l;
        half4v y;
        #pragma unroll
        for (int k = 0; k < 4; k++)
            y[k] = (_Float16)(((float)a0[k] + (float)a1[k]) * inv);
        *(half4v*)(ys + p * 264 + cg) = y;
    }
    __syncthreads();
    float4v acc[2] = {};
    #pragma unroll
    for (int kc = 0; kc < 8; kc++) {
        half8v b = *(const half8v*)(ys + l16 * 264 + kc * 32 + quad * 8);
        #pragma unroll
        for (int mt = 0; mt < 2; mt++) {
            half8v a = *(const half8v*)(wph + (w * 32 + mt * 16 + l16) * 256 + kc * 32 + quad * 8);
            acc[mt] = __builtin_amdgcn_mfma_f32_16x16x32_f16(a, b, acc[mt], 0, 0, 0);
        }
    }
    int p = p0 + l16;
    float sum = 0.f, sumsq = 0.f;
    #pragma unroll
    for (int mt = 0; mt < 2; mt++)
        #pragma unroll
        for (int r = 0; r < 4; r++) {
            int c = w * 32 + mt * 16 + quad * 4 + r;
            float v = acc[mt][r] + b_proj[c] + x[c * HW + p];
            acc[mt][r] = v;
            sum += v;
            sumsq += v * v;
        }
    sum += __shfl_xor(sum, 16, 64);
    sum += __shfl_xor(sum, 32, 64);
    sumsq += __shfl_xor(sumsq, 16, 64);
    sumsq += __shfl_xor(sumsq, 32, 64);
    if (quad == 0) { red[0][w][l16] = sum; red[1][w][l16] = sumsq; }
    __syncthreads();
    float s0 = 0.f, s1 = 0.f;
    #pragma unroll
    for (int ww = 0; ww < 16; ww++) { s0 += red[0][ww][l16]; s1 += red[1][ww][l16]; }
    float mean = s0 * (1.f / 512.f);
    float var = s1 * (1.f / 512.f) - mean * mean;
    float rstd = rsqrtf(var + LN_EPS);
    #pragma unroll
    for (int mt = 0; mt < 2; mt++)
        #pragma unroll
        for (int r = 0; r < 4; r++) {
            int c = w * 32 + mt * 16 + quad * 4 + r;
            out[c * HW + p] = (acc[mt][r] - mean) * rstd * gamma[c] + beta[c];
        }
}

extern "C" void kernel_launch(void* const* d_in, const int* in_sizes, int n_in,
                              void* d_out, int out_size, void* d_ws, size_t ws_size,
                              hipStream_t stream) {
    const float* x      = (const float*)d_in[0];
    const float* w_qkv  = (const float*)d_in[1];
    const float* w_proj = (const float*)d_in[2];
    const float* b_proj = (const float*)d_in[3];
    const float* pos_b  = (const float*)d_in[4];
    const float* gamma  = (const float*)d_in[5];
    const float* beta   = (const float*)d_in[6];
    char* ws = (char*)d_ws;
    _Float16* xt  = (_Float16*)(ws);              // 4096*512*2     = 4194304
    _Float16* qa  = (_Float16*)(ws + 4194304);    // 2097152
    _Float16* ka  = (_Float16*)(ws + 6291456);    // 2097152
    _Float16* va  = (_Float16*)(ws + 8388608);    // 2097152
    _Float16* op  = (_Float16*)(ws + 10485760);   // 2*4096*256*2   = 4194304
    float*    lp  = (float*)   (ws + 14680064);   // 2*4096*8*4     = 262144
    float*    pos = (float*)   (ws + 14942208);   // 131072
    _Float16* wqh = (_Float16*)(ws + 15073280);   // 786432
    _Float16* wph = (_Float16*)(ws + 15859712);   // 262144

    k_pre<<<896, 256, 0, stream>>>(x, w_qkv, w_proj, pos_b, xt, wqh, wph, pos);
    k_qkv<<<768, 256, 0, stream>>>(wqh, xt, qa, ka, va);
    k_attn<<<512, 256, 0, stream>>>(qa, ka, va, pos, op, lp);
    k_proj_ln<<<256, 1024, 0, stream>>>(wph, op, lp, x, b_proj, gamma, beta, (float*)d_out);
}

// Round 5
// 136.535 us; speedup vs baseline: 1.0131x; 1.0131x over previous
//
#include <hip/hip_runtime.h>
#include <hip/hip_bf16.h>
#include <math.h>

#define HW 4096
#define LN_EPS 1e-5f

typedef _Float16 half4v __attribute__((ext_vector_type(4)));
typedef _Float16 half8v __attribute__((ext_vector_type(8)));
typedef float float4v __attribute__((ext_vector_type(4)));
typedef __fp16 fp16v2 __attribute__((ext_vector_type(2)));

#if __has_builtin(__builtin_amdgcn_exp2f)
#define EXP2F(x) __builtin_amdgcn_exp2f(x)
#else
#define EXP2F(x) exp2f(x)
#endif

// ---------------- kernel 1: prep (weights f16 + pos bilinear) AND x transpose ----------
__global__ __launch_bounds__(256) void k_pre(const float* __restrict__ x,
                                             const float* __restrict__ wq,
                                             const float* __restrict__ wp,
                                             const float* __restrict__ pb,
                                             _Float16* __restrict__ xt,
                                             _Float16* __restrict__ wqh,
                                             _Float16* __restrict__ wph,
                                             float* __restrict__ pos) {
    int bx = blockIdx.x, t = threadIdx.x;
    if (bx < 512) { // transpose x [512][4096] f32 -> xt [4096][512] f16
        __shared__ _Float16 tile[64][65];
        int c0 = (bx >> 6) * 64, p0 = (bx & 63) * 64;
        int w = t >> 6, lane = t & 63;
        #pragma unroll
        for (int r = 0; r < 16; r++)
            tile[w * 16 + r][lane] = (_Float16)x[(c0 + w * 16 + r) * HW + p0 + lane];
        __syncthreads();
        int cg = (t & 15) * 4, pr = t >> 4;
        #pragma unroll
        for (int r = 0; r < 4; r++) {
            int p = pr + r * 16;
            half4v v;
            #pragma unroll
            for (int k = 0; k < 4; k++) v[k] = tile[cg + k][p];
            *(half4v*)&xt[(p0 + p) * 512 + c0 + cg] = v;
        }
        return;
    }
    int i = (bx - 512) * 256 + t;
    const float qs = 0.17677669529663687f * 1.4426950408889634f; // scale * log2(e)
    if (i < 49152) { // wq: 768*512/8 chunks; Q rows pre-scaled
        float s = (i < 16384) ? qs : 1.0f;
        float4v a = *(const float4v*)(wq + i * 8);
        float4v b = *(const float4v*)(wq + i * 8 + 4);
        half8v h;
        #pragma unroll
        for (int k = 0; k < 4; k++) { h[k] = (_Float16)(a[k] * s); h[4 + k] = (_Float16)(b[k] * s); }
        *(half8v*)(wqh + i * 8) = h;
    } else if (i < 65536) { // wp
        int j = i - 49152;
        float4v a = *(const float4v*)(wp + j * 8);
        float4v b = *(const float4v*)(wp + j * 8 + 4);
        half8v h;
        #pragma unroll
        for (int k = 0; k < 4; k++) { h[k] = (_Float16)a[k]; h[4 + k] = (_Float16)b[k]; }
        *(half8v*)(wph + j * 8) = h;
    } else { // pos bilinear 16->64, times log2(e)
        int j = i - 65536;
        int h = j >> 12, p = j & 4095, y = p >> 6, xx = p & 63;
        float sy = y * 0.25f - 0.375f, sx = xx * 0.25f - 0.375f;
        float fy = floorf(sy), fx = floorf(sx);
        float wy = sy - fy, wx = sx - fx;
        int y0 = (int)fy, x0 = (int)fx;
        int y1 = y0 + 1 < 15 ? y0 + 1 : 15;
        int x1 = x0 + 1 < 15 ? x0 + 1 : 15;
        y0 = y0 > 0 ? y0 : 0;
        x0 = x0 > 0 ? x0 : 0;
        const float* src = pb + h * 256;
        float v = (1.f - wy) * ((1.f - wx) * src[y0 * 16 + x0] + wx * src[y0 * 16 + x1]) +
                  wy * ((1.f - wx) * src[y1 * 16 + x0] + wx * src[y1 * 16 + x1]);
        pos[j] = v * 1.4426950408889634f;
    }
}

// ---------------- kernel 2: QKV GEMM, LDS-free, 64n x 128p tiles (grid 384) -----------
// Outputs: qa [h][q][d] row-major; ka/va as raw MFMA fragment streams per 32-j pair:
//   ka: pair record = 2 windows x 512 halfs. Window w (0/1) holds j's with ((j&7)>>2)==w,
//       MFMA-local row = (j5>>3)*4 + (j5&3); lane=(d>>3)*16+row, idx=d&7  (K=32 A-frag)
//   va: pair record = 1024 halfs: [d-half (d>>4)][lane=(j5>>3)*16+(d&15)][idx=j5&7]
//       -> per-lane contiguous 16B, K=32 B-frag (k = (lane>>4)*8 + idx = j5)
__global__ __launch_bounds__(256) void k_qkv(const _Float16* __restrict__ wqh,
                                             const _Float16* __restrict__ xt,
                                             _Float16* __restrict__ qa,
                                             _Float16* __restrict__ ka,
                                             _Float16* __restrict__ va) {
    int n0 = (blockIdx.x >> 5) * 64;
    int p0 = (blockIdx.x & 31) * 128;
    int t = threadIdx.x, w = t >> 6, lane = t & 63, quad = lane >> 4, l16 = lane & 15;

    const _Float16* aptr0 = xt + (p0 + w * 16 + l16) * 512 + quad * 8;
    const _Float16* aptr1 = aptr0 + 64 * 512;
    const _Float16* bptr = wqh + (n0 + l16) * 512 + quad * 8;

    float4v acc[2][4] = {};
    #pragma unroll 4
    for (int kc = 0; kc < 16; kc++) {
        half8v a0 = *(const half8v*)(aptr0 + kc * 32);
        half8v a1 = *(const half8v*)(aptr1 + kc * 32);
        #pragma unroll
        for (int nt = 0; nt < 4; nt++) {
            half8v b = *(const half8v*)(bptr + nt * 16 * 512 + kc * 32);
            acc[0][nt] = __builtin_amdgcn_mfma_f32_16x16x32_f16(a0, b, acc[0][nt], 0, 0, 0);
            acc[1][nt] = __builtin_amdgcn_mfma_f32_16x16x32_f16(a1, b, acc[1][nt], 0, 0, 0);
        }
    }
    #pragma unroll
    for (int ps = 0; ps < 2; ps++) {
        #pragma unroll
        for (int nt = 0; nt < 4; nt++) {
            int o = n0 + nt * 16 + l16;
            #pragma unroll
            for (int r = 0; r < 4; r++) {
                int p = p0 + ps * 64 + w * 16 + quad * 4 + r;
                _Float16 v = (_Float16)acc[ps][nt][r];
                if (o < 256) {
                    qa[(o >> 5) * 131072 + p * 32 + (o & 31)] = v;
                } else if (o < 512) {
                    int oc = o - 256, hh = oc >> 5, d = oc & 31;
                    int p5 = p & 31, pair = p >> 5;
                    int window = (p5 >> 2) & 1;
                    int localrow = (p5 >> 3) * 4 + (p5 & 3);
                    ka[hh * 131072 + (pair * 2 + window) * 512 +
                       ((d >> 3) * 16 + localrow) * 8 + (d & 7)] = v;
                } else {
                    int oc = o - 512, hh = oc >> 5, d = oc & 31;
                    int p5 = p & 31, pair = p >> 5;
                    va[hh * 131072 + pair * 1024 + (d >> 4) * 512 +
                       ((p5 >> 3) * 16 + (d & 15)) * 8 + (p5 & 7)] = v;
                }
            }
        }
    }
}

// ---------------- kernel 3: flash attention, DIRECT L1/L2 fragment loads, no LDS ------
// grid 1024 = 8 heads x 4 j-quarters x 32 q-blocks; block = 128 q (4 waves x 32 q).
// ka/va are stored in exact MFMA fragment order -> global read (base + lane*8) is a
// perfectly coalesced 1KB/wave load. K/V tile (16KB) is L1-resident; 4 waves reuse lines.
// No __shared__, no __syncthreads: pure streaming load->exp->MFMA, compiler pipelines.
__global__ __launch_bounds__(256, 4) void k_attn(const _Float16* __restrict__ qa,
                                                 const _Float16* __restrict__ ka,
                                                 const _Float16* __restrict__ va,
                                                 const float* __restrict__ pos,
                                                 _Float16* __restrict__ op,
                                                 float* __restrict__ lp) {
    int h = blockIdx.x & 7;
    int jq = (blockIdx.x >> 3) & 3;
    int qb = blockIdx.x >> 5;
    int t = threadIdx.x, w = t >> 6, lane = t & 63, quad = lane >> 4, l16 = lane & 15;
    int q0 = qb * 128 + w * 32;

    _Float16* opp = op + jq * 1048576;
    float* lpp = lp + jq * 32768;

    half8v qf0 = *(const half8v*)(qa + h * 131072 + (q0 + l16) * 32 + quad * 8);
    half8v qf1 = *(const half8v*)(qa + h * 131072 + (q0 + 16 + l16) * 32 + quad * 8);

    const _Float16* kg = ka + h * 131072 + jq * 32768;
    const _Float16* vg = va + h * 131072 + jq * 32768;
    const float* pq = pos + h * HW + jq * 1024;

    float4v o00 = {}, o01 = {}, o10 = {}, o11 = {};
    float4v lacc0 = {}, lacc1 = {};
    const half8v ones8 = {(_Float16)1.f, (_Float16)1.f, (_Float16)1.f, (_Float16)1.f,
                          (_Float16)1.f, (_Float16)1.f, (_Float16)1.f, (_Float16)1.f};

    #pragma unroll 2
    for (int tile = 0; tile < 8; tile++) {
        #pragma unroll
        for (int pp = 0; pp < 4; pp++) {
            const _Float16* kb = kg + tile * 4096 + pp * 1024;
            const _Float16* vb = vg + tile * 4096 + pp * 1024;
            half8v kf0 = *(const half8v*)(kb + lane * 8);        // window 0: j5 = 8*quad + r
            half8v kf1 = *(const half8v*)(kb + 512 + lane * 8);  // window 1: j5 = 8*quad + 4 + r
            half8v vlo = *(const half8v*)(vb + lane * 8);        // V B-frag, d 0..15
            half8v vhi = *(const half8v*)(vb + 512 + lane * 8);  // V B-frag, d 16..31
            float4v pb0 = *(const float4v*)(pq + tile * 128 + pp * 32 + quad * 8);
            float4v pb1 = *(const float4v*)(pq + tile * 128 + pp * 32 + quad * 8 + 4);

            // S^T (rows j, cols q); pos[j] pre-added via C operand
            __builtin_amdgcn_s_setprio(1);
            float4v s00 = __builtin_amdgcn_mfma_f32_16x16x32_f16(kf0, qf0, pb0, 0, 0, 0);
            float4v s01 = __builtin_amdgcn_mfma_f32_16x16x32_f16(kf0, qf1, pb0, 0, 0, 0);
            float4v s10 = __builtin_amdgcn_mfma_f32_16x16x32_f16(kf1, qf0, pb1, 0, 0, 0);
            float4v s11 = __builtin_amdgcn_mfma_f32_16x16x32_f16(kf1, qf1, pb1, 0, 0, 0);
            __builtin_amdgcn_s_setprio(0);

            float e0 = EXP2F(s00[0]), e1 = EXP2F(s00[1]), e2 = EXP2F(s00[2]), e3 = EXP2F(s00[3]);
            float e4 = EXP2F(s10[0]), e5 = EXP2F(s10[1]), e6 = EXP2F(s10[2]), e7 = EXP2F(s10[3]);
            float f0 = EXP2F(s01[0]), f1 = EXP2F(s01[1]), f2 = EXP2F(s01[2]), f3 = EXP2F(s01[3]);
            float f4 = EXP2F(s11[0]), f5 = EXP2F(s11[1]), f6 = EXP2F(s11[2]), f7 = EXP2F(s11[3]);

            fp16v2 a01 = __builtin_amdgcn_cvt_pkrtz(e0, e1);
            fp16v2 a23 = __builtin_amdgcn_cvt_pkrtz(e2, e3);
            fp16v2 a45 = __builtin_amdgcn_cvt_pkrtz(e4, e5);
            fp16v2 a67 = __builtin_amdgcn_cvt_pkrtz(e6, e7);
            fp16v2 b01 = __builtin_amdgcn_cvt_pkrtz(f0, f1);
            fp16v2 b23 = __builtin_amdgcn_cvt_pkrtz(f2, f3);
            fp16v2 b45 = __builtin_amdgcn_cvt_pkrtz(f4, f5);
            fp16v2 b67 = __builtin_amdgcn_cvt_pkrtz(f6, f7);

            // K=32 A-fragment: k = quad*8 + i; i 0..3 <- window0 (j5=8q+i), i 4..7 <- window1
            half4v pA0 = __builtin_bit_cast(half4v, __builtin_shufflevector(a01, a23, 0, 1, 2, 3));
            half4v pA1 = __builtin_bit_cast(half4v, __builtin_shufflevector(a45, a67, 0, 1, 2, 3));
            half8v pa0 = __builtin_shufflevector(pA0, pA1, 0, 1, 2, 3, 4, 5, 6, 7);
            half4v pB0 = __builtin_bit_cast(half4v, __builtin_shufflevector(b01, b23, 0, 1, 2, 3));
            half4v pB1 = __builtin_bit_cast(half4v, __builtin_shufflevector(b45, b67, 0, 1, 2, 3));
            half8v pa1 = __builtin_shufflevector(pB0, pB1, 0, 1, 2, 3, 4, 5, 6, 7);

            __builtin_amdgcn_s_setprio(1);
            o00 = __builtin_amdgcn_mfma_f32_16x16x32_f16(pa0, vlo, o00, 0, 0, 0);
            o01 = __builtin_amdgcn_mfma_f32_16x16x32_f16(pa0, vhi, o01, 0, 0, 0);
            o10 = __builtin_amdgcn_mfma_f32_16x16x32_f16(pa1, vlo, o10, 0, 0, 0);
            o11 = __builtin_amdgcn_mfma_f32_16x16x32_f16(pa1, vhi, o11, 0, 0, 0);
            // row-sums: D[q][n] = sum_k P[q][k] * 1  (all n cols identical)
            lacc0 = __builtin_amdgcn_mfma_f32_16x16x32_f16(pa0, ones8, lacc0, 0, 0, 0);
            lacc1 = __builtin_amdgcn_mfma_f32_16x16x32_f16(pa1, ones8, lacc1, 0, 0, 0);
            __builtin_amdgcn_s_setprio(0);
        }
    }
    #pragma unroll
    for (int r = 0; r < 4; r++) {
        int qr = quad * 4 + r;
        int qi0 = q0 + qr, qi1 = q0 + 16 + qr;
        opp[qi0 * 256 + h * 32 + l16] = (_Float16)o00[r];
        opp[qi0 * 256 + h * 32 + 16 + l16] = (_Float16)o01[r];
        opp[qi1 * 256 + h * 32 + l16] = (_Float16)o10[r];
        opp[qi1 * 256 + h * 32 + 16 + l16] = (_Float16)o11[r];
    }
    if (l16 == 0) {
        #pragma unroll
        for (int r = 0; r < 4; r++) {
            lpp[(q0 + quad * 4 + r) * 8 + h] = lacc0[r];
            lpp[(q0 + 16 + quad * 4 + r) * 8 + h] = lacc1[r];
        }
    }
}

// ---------------- kernel 4: combine 4 partials + proj GEMM + residual + LayerNorm ------
__global__ __launch_bounds__(1024) void k_proj_ln(const _Float16* __restrict__ wph,
                                                  const _Float16* __restrict__ op,
                                                  const float* __restrict__ lp,
                                                  const float* __restrict__ x,
                                                  const float* __restrict__ b_proj,
                                                  const float* __restrict__ gamma,
                                                  const float* __restrict__ beta,
                                                  float* __restrict__ out) {
    __shared__ __attribute__((aligned(16))) _Float16 ys[16 * 264];
    __shared__ float red[2][16][17];
    int p0 = blockIdx.x * 16;
    int t = threadIdx.x, w = t >> 6, lane = t & 63, quad = lane >> 4, l16 = lane & 15;
    {
        int p = t >> 6, cg = (t & 63) * 4;
        int pi = p0 + p;
        half4v a0 = *(const half4v*)(op + pi * 256 + cg);
        half4v a1 = *(const half4v*)(op + 1048576 + pi * 256 + cg);
        half4v a2 = *(const half4v*)(op + 2097152 + pi * 256 + cg);
        half4v a3 = *(const half4v*)(op + 3145728 + pi * 256 + cg);
        int hh = cg >> 5;
        float l = lp[pi * 8 + hh] + lp[32768 + pi * 8 + hh] +
                  lp[65536 + pi * 8 + hh] + lp[98304 + pi * 8 + hh];
        float inv = 1.f / l;
        half4v y;
        #pragma unroll
        for (int k = 0; k < 4; k++)
            y[k] = (_Float16)((((float)a0[k] + (float)a1[k]) +
                               ((float)a2[k] + (float)a3[k])) * inv);
        *(half4v*)(ys + p * 264 + cg) = y;
    }
    __syncthreads();
    float4v acc[2] = {};
    #pragma unroll
    for (int kc = 0; kc < 8; kc++) {
        half8v b = *(const half8v*)(ys + l16 * 264 + kc * 32 + quad * 8);
        #pragma unroll
        for (int mt = 0; mt < 2; mt++) {
            half8v a = *(const half8v*)(wph + (w * 32 + mt * 16 + l16) * 256 + kc * 32 + quad * 8);
            acc[mt] = __builtin_amdgcn_mfma_f32_16x16x32_f16(a, b, acc[mt], 0, 0, 0);
        }
    }
    int p = p0 + l16;
    float sum = 0.f, sumsq = 0.f;
    #pragma unroll
    for (int mt = 0; mt < 2; mt++)
        #pragma unroll
        for (int r = 0; r < 4; r++) {
            int c = w * 32 + mt * 16 + quad * 4 + r;
            float v = acc[mt][r] + b_proj[c] + x[c * HW + p];
            acc[mt][r] = v;
            sum += v;
            sumsq += v * v;
        }
    sum += __shfl_xor(sum, 16, 64);
    sum += __shfl_xor(sum, 32, 64);
    sumsq += __shfl_xor(sumsq, 16, 64);
    sumsq += __shfl_xor(sumsq, 32, 64);
    if (quad == 0) { red[0][w][l16] = sum; red[1][w][l16] = sumsq; }
    __syncthreads();
    float s0 = 0.f, s1 = 0.f;
    #pragma unroll
    for (int ww = 0; ww < 16; ww++) { s0 += red[0][ww][l16]; s1 += red[1][ww][l16]; }
    float mean = s0 * (1.f / 512.f);
    float var = s1 * (1.f / 512.f) - mean * mean;
    float rstd = rsqrtf(var + LN_EPS);
    #pragma unroll
    for (int mt = 0; mt < 2; mt++)
        #pragma unroll
        for (int r = 0; r < 4; r++) {
            int c = w * 32 + mt * 16 + quad * 4 + r;
            out[c * HW + p] = (acc[mt][r] - mean) * rstd * gamma[c] + beta[c];
        }
}

extern "C" void kernel_launch(void* const* d_in, const int* in_sizes, int n_in,
                              void* d_out, int out_size, void* d_ws, size_t ws_size,
                              hipStream_t stream) {
    const float* x      = (const float*)d_in[0];
    const float* w_qkv  = (const float*)d_in[1];
    const float* w_proj = (const float*)d_in[2];
    const float* b_proj = (const float*)d_in[3];
    const float* pos_b  = (const float*)d_in[4];
    const float* gamma  = (const float*)d_in[5];
    const float* beta   = (const float*)d_in[6];
    char* ws = (char*)d_ws;
    _Float16* xt  = (_Float16*)(ws);              // 4096*512*2     = 4194304
    _Float16* qa  = (_Float16*)(ws + 4194304);    // 2097152
    _Float16* ka  = (_Float16*)(ws + 6291456);    // 2097152
    _Float16* va  = (_Float16*)(ws + 8388608);    // 2097152
    _Float16* op  = (_Float16*)(ws + 10485760);   // 4*4096*256*2   = 8388608
    float*    lp  = (float*)   (ws + 18874368);   // 4*4096*8*4     = 524288
    float*    pos = (float*)   (ws + 19398656);   // 131072
    _Float16* wqh = (_Float16*)(ws + 19529728);   // 786432
    _Float16* wph = (_Float16*)(ws + 20316160);   // 262144

    k_pre<<<896, 256, 0, stream>>>(x, w_qkv, w_proj, pos_b, xt, wqh, wph, pos);
    k_qkv<<<384, 256, 0, stream>>>(wqh, xt, qa, ka, va);
    k_attn<<<1024, 256, 0, stream>>>(qa, ka, va, pos, op, lp);
    k_proj_ln<<<256, 1024, 0, stream>>>(wph, op, lp, x, b_proj, gamma, beta, (float*)d_out);
}

// Round 6
// 133.874 us; speedup vs baseline: 1.0332x; 1.0199x over previous
//
#include <hip/hip_runtime.h>
#include <hip/hip_bf16.h>
#include <math.h>

#define HW 4096
#define LN_EPS 1e-5f

typedef _Float16 half4v __attribute__((ext_vector_type(4)));
typedef _Float16 half8v __attribute__((ext_vector_type(8)));
typedef float float4v __attribute__((ext_vector_type(4)));
typedef __fp16 fp16v2 __attribute__((ext_vector_type(2)));

#if __has_builtin(__builtin_amdgcn_exp2f)
#define EXP2F(x) __builtin_amdgcn_exp2f(x)
#else
#define EXP2F(x) exp2f(x)
#endif

// async global->LDS: each lane deposits 16B at ldsbase + lane*16
__device__ __forceinline__ void gload_lds16(const _Float16* g, _Float16* l) {
#if __has_builtin(__builtin_amdgcn_global_load_lds)
    __builtin_amdgcn_global_load_lds(
        (const __attribute__((address_space(1))) void*)(const void*)g,
        (__attribute__((address_space(3))) void*)(void*)l, 16, 0, 0);
#else
    int lane = threadIdx.x & 63;
    *(half8v*)(l + lane * 8) = *(const half8v*)g;
#endif
}

// ---------------- kernel 1: prep (weights f16 + pos bilinear) AND x transpose ----------
__global__ __launch_bounds__(256) void k_pre(const float* __restrict__ x,
                                             const float* __restrict__ wq,
                                             const float* __restrict__ wp,
                                             const float* __restrict__ pb,
                                             _Float16* __restrict__ xt,
                                             _Float16* __restrict__ wqh,
                                             _Float16* __restrict__ wph,
                                             float* __restrict__ pos) {
    int bx = blockIdx.x, t = threadIdx.x;
    if (bx < 512) { // transpose x [512][4096] f32 -> xt [4096][512] f16
        __shared__ _Float16 tile[64][65];
        int c0 = (bx >> 6) * 64, p0 = (bx & 63) * 64;
        int w = t >> 6, lane = t & 63;
        #pragma unroll
        for (int r = 0; r < 16; r++)
            tile[w * 16 + r][lane] = (_Float16)x[(c0 + w * 16 + r) * HW + p0 + lane];
        __syncthreads();
        int cg = (t & 15) * 4, pr = t >> 4;
        #pragma unroll
        for (int r = 0; r < 4; r++) {
            int p = pr + r * 16;
            half4v v;
            #pragma unroll
            for (int k = 0; k < 4; k++) v[k] = tile[cg + k][p];
            *(half4v*)&xt[(p0 + p) * 512 + c0 + cg] = v;
        }
        return;
    }
    int i = (bx - 512) * 256 + t;
    const float qs = 0.17677669529663687f * 1.4426950408889634f; // scale * log2(e)
    if (i < 49152) { // wq: 768*512/8 chunks; Q rows pre-scaled
        float s = (i < 16384) ? qs : 1.0f;
        float4v a = *(const float4v*)(wq + i * 8);
        float4v b = *(const float4v*)(wq + i * 8 + 4);
        half8v h;
        #pragma unroll
        for (int k = 0; k < 4; k++) { h[k] = (_Float16)(a[k] * s); h[4 + k] = (_Float16)(b[k] * s); }
        *(half8v*)(wqh + i * 8) = h;
    } else if (i < 65536) { // wp
        int j = i - 49152;
        float4v a = *(const float4v*)(wp + j * 8);
        float4v b = *(const float4v*)(wp + j * 8 + 4);
        half8v h;
        #pragma unroll
        for (int k = 0; k < 4; k++) { h[k] = (_Float16)a[k]; h[4 + k] = (_Float16)b[k]; }
        *(half8v*)(wph + j * 8) = h;
    } else { // pos bilinear 16->64, times log2(e)
        int j = i - 65536;
        int h = j >> 12, p = j & 4095, y = p >> 6, xx = p & 63;
        float sy = y * 0.25f - 0.375f, sx = xx * 0.25f - 0.375f;
        float fy = floorf(sy), fx = floorf(sx);
        float wy = sy - fy, wx = sx - fx;
        int y0 = (int)fy, x0 = (int)fx;
        int y1 = y0 + 1 < 15 ? y0 + 1 : 15;
        int x1 = x0 + 1 < 15 ? x0 + 1 : 15;
        y0 = y0 > 0 ? y0 : 0;
        x0 = x0 > 0 ? x0 : 0;
        const float* src = pb + h * 256;
        float v = (1.f - wy) * ((1.f - wx) * src[y0 * 16 + x0] + wx * src[y0 * 16 + x1]) +
                  wy * ((1.f - wx) * src[y1 * 16 + x0] + wx * src[y1 * 16 + x1]);
        pos[j] = v * 1.4426950408889634f;
    }
}

// ---------------- kernel 2: QKV GEMM, LDS-free, 64n x 128p tiles ----------------------
// Outputs: qa [h][q][d] row-major; ka/va as raw MFMA fragment streams per 32-j pair:
//   ka: pair record = 2 windows x 512 halfs. Window w (0/1) holds j's with ((j&7)>>2)==w,
//       MFMA-local row = (j5>>3)*4 + (j5&3); lane=(d>>3)*16+row, idx=d&7  (K=32 A-frag)
//   va: pair record = 1024 halfs: [d-half (d>>4)][lane=(j5>>3)*16+(d&15)][idx=j5&7]
//       -> per-lane contiguous 16B, K=32 B-frag (k = (lane>>4)*8 + idx = j5)
__global__ __launch_bounds__(256) void k_qkv(const _Float16* __restrict__ wqh,
                                             const _Float16* __restrict__ xt,
                                             _Float16* __restrict__ qa,
                                             _Float16* __restrict__ ka,
                                             _Float16* __restrict__ va) {
    int n0 = (blockIdx.x >> 5) * 64;
    int p0 = (blockIdx.x & 31) * 128;
    int t = threadIdx.x, w = t >> 6, lane = t & 63, quad = lane >> 4, l16 = lane & 15;

    const _Float16* aptr0 = xt + (p0 + w * 16 + l16) * 512 + quad * 8;
    const _Float16* aptr1 = aptr0 + 64 * 512;
    const _Float16* bptr = wqh + (n0 + l16) * 512 + quad * 8;

    float4v acc[2][4] = {};
    #pragma unroll 4
    for (int kc = 0; kc < 16; kc++) {
        half8v a0 = *(const half8v*)(aptr0 + kc * 32);
        half8v a1 = *(const half8v*)(aptr1 + kc * 32);
        #pragma unroll
        for (int nt = 0; nt < 4; nt++) {
            half8v b = *(const half8v*)(bptr + nt * 16 * 512 + kc * 32);
            acc[0][nt] = __builtin_amdgcn_mfma_f32_16x16x32_f16(a0, b, acc[0][nt], 0, 0, 0);
            acc[1][nt] = __builtin_amdgcn_mfma_f32_16x16x32_f16(a1, b, acc[1][nt], 0, 0, 0);
        }
    }
    #pragma unroll
    for (int ps = 0; ps < 2; ps++) {
        #pragma unroll
        for (int nt = 0; nt < 4; nt++) {
            int o = n0 + nt * 16 + l16;
            #pragma unroll
            for (int r = 0; r < 4; r++) {
                int p = p0 + ps * 64 + w * 16 + quad * 4 + r;
                _Float16 v = (_Float16)acc[ps][nt][r];
                if (o < 256) {
                    qa[(o >> 5) * 131072 + p * 32 + (o & 31)] = v;
                } else if (o < 512) {
                    int oc = o - 256, hh = oc >> 5, d = oc & 31;
                    int p5 = p & 31, pair = p >> 5;
                    int window = (p5 >> 2) & 1;
                    int localrow = (p5 >> 3) * 4 + (p5 & 3);
                    ka[hh * 131072 + (pair * 2 + window) * 512 +
                       ((d >> 3) * 16 + localrow) * 8 + (d & 7)] = v;
                } else {
                    int oc = o - 512, hh = oc >> 5, d = oc & 31;
                    int p5 = p & 31, pair = p >> 5;
                    va[hh * 131072 + pair * 1024 + (d >> 4) * 512 +
                       ((p5 >> 3) * 16 + (d & 15)) * 8 + (p5 & 7)] = v;
                }
            }
        }
    }
}

// ---------------- kernel 3: flash attention, async-LDS double buffer, j-split x4 -------
// grid 1024 = 8 heads x 4 j-quarters x 32 q-blocks; block = 128 q (4 waves x 32 q).
// 128-j tiles (8 iterations), paired-window K=32 PV MFMAs, f16 partial outputs.
// lsum computed via MFMA with all-ones B fragment (no fdot2 chain, no shfl reduce).
__global__ __launch_bounds__(256, 4) void k_attn(const _Float16* __restrict__ qa,
                                                 const _Float16* __restrict__ ka,
                                                 const _Float16* __restrict__ va,
                                                 const float* __restrict__ pos,
                                                 _Float16* __restrict__ op,
                                                 float* __restrict__ lp) {
    __shared__ __attribute__((aligned(16))) _Float16 kbuf[2][4096];
    __shared__ __attribute__((aligned(16))) _Float16 vbuf[2][4096];
    __shared__ __attribute__((aligned(16))) float posl[1024];
    int h = blockIdx.x & 7;
    int jq = (blockIdx.x >> 3) & 3;
    int qb = blockIdx.x >> 5;
    int t = threadIdx.x, w = t >> 6, lane = t & 63, quad = lane >> 4, l16 = lane & 15;
    int q0 = qb * 128 + w * 32;

    _Float16* opp = op + jq * 1048576;
    float* lpp = lp + jq * 32768;

    // stage pos quarter (1024 floats)
    *(float4v*)(posl + t * 4) = *(const float4v*)(pos + h * HW + jq * 1024 + t * 4);

    half8v qf0 = *(const half8v*)(qa + h * 131072 + (q0 + l16) * 32 + quad * 8);
    half8v qf1 = *(const half8v*)(qa + h * 131072 + (q0 + 16 + l16) * 32 + quad * 8);

    const _Float16* kg = ka + h * 131072 + jq * 32768;
    const _Float16* vg = va + h * 131072 + jq * 32768;

    // issue tile 0 loads (async into LDS): 8 KB each of K and V
    gload_lds16(kg + (w * 64 + lane) * 8, &kbuf[0][w * 512]);
    gload_lds16(kg + 2048 + (w * 64 + lane) * 8, &kbuf[0][2048 + w * 512]);
    gload_lds16(vg + (w * 64 + lane) * 8, &vbuf[0][w * 512]);
    gload_lds16(vg + 2048 + (w * 64 + lane) * 8, &vbuf[0][2048 + w * 512]);

    float4v o00 = {}, o01 = {}, o10 = {}, o11 = {};
    float4v lacc0 = {}, lacc1 = {};
    const half8v ones8 = {(_Float16)1.f, (_Float16)1.f, (_Float16)1.f, (_Float16)1.f,
                          (_Float16)1.f, (_Float16)1.f, (_Float16)1.f, (_Float16)1.f};

    for (int tile = 0; tile < 8; tile++) {
        int buf = tile & 1;
        __syncthreads(); // drains this tile's async loads (vmcnt) + prior LDS reads
        if (tile + 1 < 8) {
            const _Float16* kn = kg + (tile + 1) * 4096;
            const _Float16* vn = vg + (tile + 1) * 4096;
            gload_lds16(kn + (w * 64 + lane) * 8, &kbuf[buf ^ 1][w * 512]);
            gload_lds16(kn + 2048 + (w * 64 + lane) * 8, &kbuf[buf ^ 1][2048 + w * 512]);
            gload_lds16(vn + (w * 64 + lane) * 8, &vbuf[buf ^ 1][w * 512]);
            gload_lds16(vn + 2048 + (w * 64 + lane) * 8, &vbuf[buf ^ 1][2048 + w * 512]);
        }
        #pragma unroll
        for (int pp = 0; pp < 4; pp++) {
            const _Float16* kb = &kbuf[buf][pp * 1024];
            const _Float16* vb = &vbuf[buf][pp * 1024];
            half8v kf0 = *(const half8v*)(kb + lane * 8);        // window 0: j5 = 8*quad + r
            half8v kf1 = *(const half8v*)(kb + 512 + lane * 8);  // window 1: j5 = 8*quad + 4 + r
            half8v vlo = *(const half8v*)(vb + lane * 8);        // V B-frag, d 0..15
            half8v vhi = *(const half8v*)(vb + 512 + lane * 8);  // V B-frag, d 16..31
            float4v pb0 = *(const float4v*)(posl + tile * 128 + pp * 32 + quad * 8);
            float4v pb1 = *(const float4v*)(posl + tile * 128 + pp * 32 + quad * 8 + 4);

            // S^T (rows j, cols q); pos[j] pre-added via C operand
            __builtin_amdgcn_s_setprio(1);
            float4v s00 = __builtin_amdgcn_mfma_f32_16x16x32_f16(kf0, qf0, pb0, 0, 0, 0);
            float4v s01 = __builtin_amdgcn_mfma_f32_16x16x32_f16(kf0, qf1, pb0, 0, 0, 0);
            float4v s10 = __builtin_amdgcn_mfma_f32_16x16x32_f16(kf1, qf0, pb1, 0, 0, 0);
            float4v s11 = __builtin_amdgcn_mfma_f32_16x16x32_f16(kf1, qf1, pb1, 0, 0, 0);
            __builtin_amdgcn_s_setprio(0);

            float e0 = EXP2F(s00[0]), e1 = EXP2F(s00[1]), e2 = EXP2F(s00[2]), e3 = EXP2F(s00[3]);
            float e4 = EXP2F(s10[0]), e5 = EXP2F(s10[1]), e6 = EXP2F(s10[2]), e7 = EXP2F(s10[3]);
            float f0 = EXP2F(s01[0]), f1 = EXP2F(s01[1]), f2 = EXP2F(s01[2]), f3 = EXP2F(s01[3]);
            float f4 = EXP2F(s11[0]), f5 = EXP2F(s11[1]), f6 = EXP2F(s11[2]), f7 = EXP2F(s11[3]);

            fp16v2 a01 = __builtin_amdgcn_cvt_pkrtz(e0, e1);
            fp16v2 a23 = __builtin_amdgcn_cvt_pkrtz(e2, e3);
            fp16v2 a45 = __builtin_amdgcn_cvt_pkrtz(e4, e5);
            fp16v2 a67 = __builtin_amdgcn_cvt_pkrtz(e6, e7);
            fp16v2 b01 = __builtin_amdgcn_cvt_pkrtz(f0, f1);
            fp16v2 b23 = __builtin_amdgcn_cvt_pkrtz(f2, f3);
            fp16v2 b45 = __builtin_amdgcn_cvt_pkrtz(f4, f5);
            fp16v2 b67 = __builtin_amdgcn_cvt_pkrtz(f6, f7);

            // K=32 A-fragment: k = quad*8 + i; i 0..3 <- window0 (j5=8q+i), i 4..7 <- window1
            half4v pA0 = __builtin_bit_cast(half4v, __builtin_shufflevector(a01, a23, 0, 1, 2, 3));
            half4v pA1 = __builtin_bit_cast(half4v, __builtin_shufflevector(a45, a67, 0, 1, 2, 3));
            half8v pa0 = __builtin_shufflevector(pA0, pA1, 0, 1, 2, 3, 4, 5, 6, 7);
            half4v pB0 = __builtin_bit_cast(half4v, __builtin_shufflevector(b01, b23, 0, 1, 2, 3));
            half4v pB1 = __builtin_bit_cast(half4v, __builtin_shufflevector(b45, b67, 0, 1, 2, 3));
            half8v pa1 = __builtin_shufflevector(pB0, pB1, 0, 1, 2, 3, 4, 5, 6, 7);

            __builtin_amdgcn_s_setprio(1);
            o00 = __builtin_amdgcn_mfma_f32_16x16x32_f16(pa0, vlo, o00, 0, 0, 0);
            o01 = __builtin_amdgcn_mfma_f32_16x16x32_f16(pa0, vhi, o01, 0, 0, 0);
            o10 = __builtin_amdgcn_mfma_f32_16x16x32_f16(pa1, vlo, o10, 0, 0, 0);
            o11 = __builtin_amdgcn_mfma_f32_16x16x32_f16(pa1, vhi, o11, 0, 0, 0);
            // row-sums: D[q][n] = sum_k P[q][k] * 1  (all n cols identical)
            lacc0 = __builtin_amdgcn_mfma_f32_16x16x32_f16(pa0, ones8, lacc0, 0, 0, 0);
            lacc1 = __builtin_amdgcn_mfma_f32_16x16x32_f16(pa1, ones8, lacc1, 0, 0, 0);
            __builtin_amdgcn_s_setprio(0);
        }
    }
    #pragma unroll
    for (int r = 0; r < 4; r++) {
        int qr = quad * 4 + r;
        int qi0 = q0 + qr, qi1 = q0 + 16 + qr;
        opp[qi0 * 256 + h * 32 + l16] = (_Float16)o00[r];
        opp[qi0 * 256 + h * 32 + 16 + l16] = (_Float16)o01[r];
        opp[qi1 * 256 + h * 32 + l16] = (_Float16)o10[r];
        opp[qi1 * 256 + h * 32 + 16 + l16] = (_Float16)o11[r];
    }
    if (l16 == 0) {
        #pragma unroll
        for (int r = 0; r < 4; r++) {
            lpp[(q0 + quad * 4 + r) * 8 + h] = lacc0[r];
            lpp[(q0 + 16 + quad * 4 + r) * 8 + h] = lacc1[r];
        }
    }
}

// ---------------- kernel 4: combine 4 partials + proj GEMM + residual + LayerNorm ------
__global__ __launch_bounds__(1024) void k_proj_ln(const _Float16* __restrict__ wph,
                                                  const _Float16* __restrict__ op,
                                                  const float* __restrict__ lp,
                                                  const float* __restrict__ x,
                                                  const float* __restrict__ b_proj,
                                                  const float* __restrict__ gamma,
                                                  const float* __restrict__ beta,
                                                  float* __restrict__ out) {
    __shared__ __attribute__((aligned(16))) _Float16 ys[16 * 264];
    __shared__ float red[2][16][17];
    int p0 = blockIdx.x * 16;
    int t = threadIdx.x, w = t >> 6, lane = t & 63, quad = lane >> 4, l16 = lane & 15;
    {
        int p = t >> 6, cg = (t & 63) * 4;
        int pi = p0 + p;
        half4v a0 = *(const half4v*)(op + pi * 256 + cg);
        half4v a1 = *(const half4v*)(op + 1048576 + pi * 256 + cg);
        half4v a2 = *(const half4v*)(op + 2097152 + pi * 256 + cg);
        half4v a3 = *(const half4v*)(op + 3145728 + pi * 256 + cg);
        int hh = cg >> 5;
        float l = lp[pi * 8 + hh] + lp[32768 + pi * 8 + hh] +
                  lp[65536 + pi * 8 + hh] + lp[98304 + pi * 8 + hh];
        float inv = 1.f / l;
        half4v y;
        #pragma unroll
        for (int k = 0; k < 4; k++)
            y[k] = (_Float16)((((float)a0[k] + (float)a1[k]) +
                               ((float)a2[k] + (float)a3[k])) * inv);
        *(half4v*)(ys + p * 264 + cg) = y;
    }
    __syncthreads();
    float4v acc[2] = {};
    #pragma unroll
    for (int kc = 0; kc < 8; kc++) {
        half8v b = *(const half8v*)(ys + l16 * 264 + kc * 32 + quad * 8);
        #pragma unroll
        for (int mt = 0; mt < 2; mt++) {
            half8v a = *(const half8v*)(wph + (w * 32 + mt * 16 + l16) * 256 + kc * 32 + quad * 8);
            acc[mt] = __builtin_amdgcn_mfma_f32_16x16x32_f16(a, b, acc[mt], 0, 0, 0);
        }
    }
    int p = p0 + l16;
    float sum = 0.f, sumsq = 0.f;
    #pragma unroll
    for (int mt = 0; mt < 2; mt++)
        #pragma unroll
        for (int r = 0; r < 4; r++) {
            int c = w * 32 + mt * 16 + quad * 4 + r;
            float v = acc[mt][r] + b_proj[c] + x[c * HW + p];
            acc[mt][r] = v;
            sum += v;
            sumsq += v * v;
        }
    sum += __shfl_xor(sum, 16, 64);
    sum += __shfl_xor(sum, 32, 64);
    sumsq += __shfl_xor(sumsq, 16, 64);
    sumsq += __shfl_xor(sumsq, 32, 64);
    if (quad == 0) { red[0][w][l16] = sum; red[1][w][l16] = sumsq; }
    __syncthreads();
    float s0 = 0.f, s1 = 0.f;
    #pragma unroll
    for (int ww = 0; ww < 16; ww++) { s0 += red[0][ww][l16]; s1 += red[1][ww][l16]; }
    float mean = s0 * (1.f / 512.f);
    float var = s1 * (1.f / 512.f) - mean * mean;
    float rstd = rsqrtf(var + LN_EPS);
    #pragma unroll
    for (int mt = 0; mt < 2; mt++)
        #pragma unroll
        for (int r = 0; r < 4; r++) {
            int c = w * 32 + mt * 16 + quad * 4 + r;
            out[c * HW + p] = (acc[mt][r] - mean) * rstd * gamma[c] + beta[c];
        }
}

extern "C" void kernel_launch(void* const* d_in, const int* in_sizes, int n_in,
                              void* d_out, int out_size, void* d_ws, size_t ws_size,
                              hipStream_t stream) {
    const float* x      = (const float*)d_in[0];
    const float* w_qkv  = (const float*)d_in[1];
    const float* w_proj = (const float*)d_in[2];
    const float* b_proj = (const float*)d_in[3];
    const float* pos_b  = (const float*)d_in[4];
    const float* gamma  = (const float*)d_in[5];
    const float* beta   = (const float*)d_in[6];
    char* ws = (char*)d_ws;
    _Float16* xt  = (_Float16*)(ws);              // 4096*512*2     = 4194304
    _Float16* qa  = (_Float16*)(ws + 4194304);    // 2097152
    _Float16* ka  = (_Float16*)(ws + 6291456);    // 2097152
    _Float16* va  = (_Float16*)(ws + 8388608);    // 2097152
    _Float16* op  = (_Float16*)(ws + 10485760);   // 4*4096*256*2   = 8388608
    float*    lp  = (float*)   (ws + 18874368);   // 4*4096*8*4     = 524288
    float*    pos = (float*)   (ws + 19398656);   // 131072
    _Float16* wqh = (_Float16*)(ws + 19529728);   // 786432
    _Float16* wph = (_Float16*)(ws + 20316160);   // 262144

    k_pre<<<896, 256, 0, stream>>>(x, w_qkv, w_proj, pos_b, xt, wqh, wph, pos);
    k_qkv<<<384, 256, 0, stream>>>(wqh, xt, qa, ka, va);
    k_attn<<<1024, 256, 0, stream>>>(qa, ka, va, pos, op, lp);
    k_proj_ln<<<256, 1024, 0, stream>>>(wph, op, lp, x, b_proj, gamma, beta, (float*)d_out);
}